// Round 3
// baseline (327.517 us; speedup 1.0000x reference)
//
#include <hip/hip_runtime.h>

typedef _Float16 h16x8 __attribute__((ext_vector_type(8)));
typedef _Float16 h16x4 __attribute__((ext_vector_type(4)));
typedef float    f32x4 __attribute__((ext_vector_type(4)));

#define NDIM   12288
#define KDIM   4096
#define MDIM   256
#define N_TILE 48
#define NT     32      // K iterations of 128 (= GROUP_SIZE)

// Pre-pass: x f32 -> f16 (exact: x was originally fp16). 1M elems, float4/thread.
__global__ __launch_bounds__(256) void cvt_x_kernel(const float* __restrict__ x,
                                                    _Float16* __restrict__ xf) {
    int i = blockIdx.x * 256 + threadIdx.x;
    f32x4 v = *(const f32x4*)(x + (size_t)i * 4);
    h16x4 h;
    h[0] = (_Float16)v[0]; h[1] = (_Float16)v[1];
    h[2] = (_Float16)v[2]; h[3] = (_Float16)v[3];
    *(h16x4*)(xf + (size_t)i * 4) = h;
}

// Block: 512 threads (8 waves), tile = all 256 tokens x 48 out-features.
// Grid: 12288/48 = 256 blocks -> each weight element read from HBM exactly once.
template<int USE_F16X>
__global__ __launch_bounds__(512) void qlin_kernel(
    const float*    __restrict__ xf32,   // [256][4096] fp32 (fp16-exact values)
    const _Float16* __restrict__ xf16,   // [256][4096] f16 (pre-converted in ws)
    const float*    __restrict__ scales, // [12288][32] fp32
    const float*    __restrict__ bias,   // [12288]     fp32
    const int*      __restrict__ wq,     // [12288][4096], values in [-128,127]
    float*          __restrict__ out)    // [256][12288] fp32
{
    // Double-buffered dequantized f16 W tile: 48 rows x 128 k, 256B/row,
    // XOR-swizzled (byte ^= (row&7)<<4) -> conflict-free b64 writes / b128 reads.
    __shared__ char  wl[2][N_TILE * 256];   // 24576 B
    __shared__ float sc[N_TILE * 32];       // 6144 B

    const int tid  = threadIdx.x;
    const int lane = tid & 63;
    const int wave = tid >> 6;              // 0..7
    const int n0   = blockIdx.x * N_TILE;

    // Preload all scales for the tile (48 rows x 32 groups), fp32 direct
    for (int j = tid; j < N_TILE * 32; j += 512)
        sc[j] = scales[(size_t)(n0 + (j >> 5)) * 32 + (j & 31)];

    // --- W staging map: thread handles rows (r0, r0+16, r0+32), 4 consecutive k each
    const int r0    = tid >> 5;             // 0..15
    const int kc    = (tid & 31) * 4;       // 0..124
    const int xorw  = (r0 & 7) << 4;
    const int wbyte = ((tid & 31) * 8) ^ xorw;

    const int* wp0 = wq + (size_t)(n0 + r0     ) * KDIM + kc;
    const int* wp1 = wq + (size_t)(n0 + r0 + 16) * KDIM + kc;
    const int* wp2 = wq + (size_t)(n0 + r0 + 32) * KDIM + kc;

    int4 q0 = *(const int4*)wp0;    // tile t=0 in flight
    int4 q1 = *(const int4*)wp1;
    int4 q2 = *(const int4*)wp2;

    __syncthreads();   // scales visible

    auto cvt_write = [&](int buf, int g) {
        float s0 = sc[(r0     ) * 32 + g];
        float s1 = sc[(r0 + 16) * 32 + g];
        float s2 = sc[(r0 + 32) * 32 + g];
        h16x4 h;
        // (half)((float)q * s_f32): identical single-rounding to ref's fp16 dequant
        h[0] = (_Float16)((float)q0.x * s0); h[1] = (_Float16)((float)q0.y * s0);
        h[2] = (_Float16)((float)q0.z * s0); h[3] = (_Float16)((float)q0.w * s0);
        *(h16x4*)(&wl[buf][(r0     ) * 256 + wbyte]) = h;
        h[0] = (_Float16)((float)q1.x * s1); h[1] = (_Float16)((float)q1.y * s1);
        h[2] = (_Float16)((float)q1.z * s1); h[3] = (_Float16)((float)q1.w * s1);
        *(h16x4*)(&wl[buf][(r0 + 16) * 256 + wbyte]) = h;
        h[0] = (_Float16)((float)q2.x * s2); h[1] = (_Float16)((float)q2.y * s2);
        h[2] = (_Float16)((float)q2.z * s2); h[3] = (_Float16)((float)q2.w * s2);
        *(h16x4*)(&wl[buf][(r0 + 32) * 256 + wbyte]) = h;
    };

    cvt_write(0, 0);

    // --- MFMA fragment addressing (16x16x32 f16)
    // A and B use the identical (lane-group,elem)->k map, so HW k-order cancels.
    const int arow = lane & 15;
    const int g16  = lane >> 4;             // 0..3
    const size_t idx0 = (size_t)(wave * 32 + arow) * KDIM + g16 * 8;   // row a0
    const int xorv = (arow & 7) << 4;       // read-side swizzle (row&7 == arow&7)

    auto load_a = [&](size_t idx) -> h16x8 {
        if constexpr (USE_F16X) {
            return *(const h16x8*)(xf16 + idx);
        } else {
            f32x4 u0 = *(const f32x4*)(xf32 + idx);
            f32x4 u1 = *(const f32x4*)(xf32 + idx + 4);
            h16x8 a;
            a[0] = (_Float16)u0[0]; a[1] = (_Float16)u0[1];
            a[2] = (_Float16)u0[2]; a[3] = (_Float16)u0[3];
            a[4] = (_Float16)u1[0]; a[5] = (_Float16)u1[1];
            a[6] = (_Float16)u1[2]; a[7] = (_Float16)u1[3];
            return a;
        }
    };

    f32x4 zero = {0.f, 0.f, 0.f, 0.f};
    f32x4 acc[2][3];
    #pragma unroll
    for (int i = 0; i < 2; ++i)
        #pragma unroll
        for (int j = 0; j < 3; ++j) acc[i][j] = zero;

    __syncthreads();   // buf0 ready

    int cur = 0;
    for (int t = 0; t < NT; ++t) {
        if (t + 1 < NT) {          // issue next W tile (one full iteration of cover)
            q0 = *(const int4*)(wp0 + (t + 1) * 128);
            q1 = *(const int4*)(wp1 + (t + 1) * 128);
            q2 = *(const int4*)(wp2 + (t + 1) * 128);
        }
        const char* wb = wl[cur];
        #pragma unroll
        for (int kk = 0; kk < 4; ++kk) {
            h16x8 a0 = load_a(idx0 + t * 128 + kk * 32);
            h16x8 a1 = load_a(idx0 + (size_t)16 * KDIM + t * 128 + kk * 32);
            #pragma unroll
            for (int ni = 0; ni < 3; ++ni) {
                h16x8 b = *(const h16x8*)(wb + (ni * 16 + arow) * 256
                                             + ((kk * 64 + g16 * 16) ^ xorv));
                acc[0][ni] = __builtin_amdgcn_mfma_f32_16x16x32_f16(a0, b, acc[0][ni], 0, 0, 0);
                acc[1][ni] = __builtin_amdgcn_mfma_f32_16x16x32_f16(a1, b, acc[1][ni], 0, 0, 0);
            }
        }
        if (t + 1 < NT) cvt_write(cur ^ 1, t + 1);
        __syncthreads();
        cur ^= 1;
    }

    // --- Epilogue: D[row][col]: col = lane&15, row = 4*(lane>>4)+r  (m89-verified)
    float bv0 = bias[n0 + arow];
    float bv1 = bias[n0 + 16 + arow];
    float bv2 = bias[n0 + 32 + arow];
    #pragma unroll
    for (int mi = 0; mi < 2; ++mi) {
        #pragma unroll
        for (int r = 0; r < 4; ++r) {
            int m = wave * 32 + mi * 16 + g16 * 4 + r;
            float* op = out + (size_t)m * NDIM + n0 + arow;
            op[0]  = acc[mi][0][r] + bv0;
            op[16] = acc[mi][1][r] + bv1;
            op[32] = acc[mi][2][r] + bv2;
        }
    }
}

extern "C" void kernel_launch(void* const* d_in, const int* in_sizes, int n_in,
                              void* d_out, int out_size, void* d_ws, size_t ws_size,
                              hipStream_t stream) {
    const float* x      = (const float*)d_in[0];
    const float* scales = (const float*)d_in[1];
    const float* bias   = (const float*)d_in[2];
    const int*   wq     = (const int*)d_in[3];
    float*       out    = (float*)d_out;

    const size_t xf_bytes = (size_t)MDIM * KDIM * sizeof(_Float16);  // 2 MB
    if (ws_size >= xf_bytes) {
        _Float16* xf = (_Float16*)d_ws;
        cvt_x_kernel<<<dim3(MDIM * KDIM / 1024), dim3(256), 0, stream>>>(x, xf);
        qlin_kernel<1><<<dim3(NDIM / N_TILE), dim3(512), 0, stream>>>(x, xf, scales, bias, wq, out);
    } else {
        qlin_kernel<0><<<dim3(NDIM / N_TILE), dim3(512), 0, stream>>>(x, nullptr, scales, bias, wq, out);
    }
}

// Round 7
// 312.506 us; speedup vs baseline: 1.0480x; 1.0480x over previous
//
#include <hip/hip_runtime.h>

typedef _Float16 h16x8 __attribute__((ext_vector_type(8)));
typedef _Float16 h16x4 __attribute__((ext_vector_type(4)));
typedef _Float16 h16x2 __attribute__((ext_vector_type(2)));
typedef float    f32x4 __attribute__((ext_vector_type(4)));

#define NDIM   12288
#define KDIM   4096
#define MDIM   256
#define N_TILE 48
#define NT     32      // K iterations of 128 (= GROUP_SIZE)

// Pre-pass: x f32 -> f16 (exact: x was originally fp16).
__global__ __launch_bounds__(256) void cvt_x_kernel(const float* __restrict__ x,
                                                    _Float16* __restrict__ xf) {
    int i = blockIdx.x * 256 + threadIdx.x;
    f32x4 v = *(const f32x4*)(x + (size_t)i * 4);
    h16x4 h;
    h[0] = (_Float16)v[0]; h[1] = (_Float16)v[1];
    h[2] = (_Float16)v[2]; h[3] = (_Float16)v[3];
    *(h16x4*)(xf + (size_t)i * 4) = h;
}

// 256 blocks x 1024 threads (16 waves = 4/SIMD). Block tile: 256 m x 48 n, full K.
// Each weight element fetched from HBM/L3 exactly once. W prefetched 2 tiles deep.
template<int USE_F16X>
__global__ __launch_bounds__(1024, 4) void qlin_kernel(
    const float*    __restrict__ xf32,   // [256][4096] fp32
    const _Float16* __restrict__ xf16,   // [256][4096] f16 (ws)
    const float*    __restrict__ scales, // [12288][32] fp32
    const float*    __restrict__ bias,   // [12288]     fp32
    const int*      __restrict__ wq,     // [12288][4096]
    float*          __restrict__ out)    // [256][12288] fp32
{
    __shared__ char  wl[2][N_TILE * 256];   // dequant f16 W, XOR-swizzled
    __shared__ float sc[N_TILE * 32];

    const int tid  = threadIdx.x;
    const int lane = tid & 63;
    const int wave = tid >> 6;              // 0..15
    const int n0   = blockIdx.x * N_TILE;

    for (int j = tid; j < N_TILE * 32; j += 1024)
        sc[j] = scales[(size_t)(n0 + (j >> 5)) * 32 + (j & 31)];

    // --- W staging: wave w stages rows {w, w+16, w+32}; one wave-inst = one full
    // row tile-slice (64 consecutive int2 = 512B contiguous). Scale is wave-uniform.
    const int2* wb0 = (const int2*)wq + (size_t)(n0 + wave     ) * 2048 + lane;
    const int2* wb1 = (const int2*)wq + (size_t)(n0 + wave + 16) * 2048 + lane;
    const int2* wb2 = (const int2*)wq + (size_t)(n0 + wave + 32) * 2048 + lane;
    const int xors  = (wave & 7) << 4;      // same for w, w+16, w+32
    const int wby0  = (wave     ) * 256 + ((lane * 4) ^ xors);
    const int wby1  = (wave + 16) * 256 + ((lane * 4) ^ xors);
    const int wby2  = (wave + 32) * 256 + ((lane * 4) ^ xors);

    auto cw = [&](int buf, int g, int2 a, int2 b, int2 c) {
        float s0 = sc[(wave     ) * 32 + g];
        float s1 = sc[(wave + 16) * 32 + g];
        float s2 = sc[(wave + 32) * 32 + g];
        h16x2 h;
        h[0] = (_Float16)((float)a.x * s0); h[1] = (_Float16)((float)a.y * s0);
        *(h16x2*)(&wl[buf][wby0]) = h;
        h[0] = (_Float16)((float)b.x * s1); h[1] = (_Float16)((float)b.y * s1);
        *(h16x2*)(&wl[buf][wby1]) = h;
        h[0] = (_Float16)((float)c.x * s2); h[1] = (_Float16)((float)c.y * s2);
        *(h16x2*)(&wl[buf][wby2]) = h;
    };

    // --- MFMA fragment addressing (16x16x32 f16); A/B share the k map -> HW order cancels
    const int arow = lane & 15;
    const int g16  = lane >> 4;
    const int xorv = (arow & 7) << 4;
    const size_t aidx0 = (size_t)(wave * 16 + arow) * KDIM + g16 * 8;

    auto load_a = [&](size_t idx) -> h16x8 {
        if constexpr (USE_F16X) {
            return *(const h16x8*)(xf16 + idx);
        } else {
            f32x4 u0 = *(const f32x4*)(xf32 + idx);
            f32x4 u1 = *(const f32x4*)(xf32 + idx + 4);
            h16x8 a;
            a[0] = (_Float16)u0[0]; a[1] = (_Float16)u0[1];
            a[2] = (_Float16)u0[2]; a[3] = (_Float16)u0[3];
            a[4] = (_Float16)u1[0]; a[5] = (_Float16)u1[1];
            a[6] = (_Float16)u1[2]; a[7] = (_Float16)u1[3];
            return a;
        }
    };

    f32x4 acc0 = {0.f,0.f,0.f,0.f}, acc1 = acc0, acc2 = acc0;

    auto mfma_phase = [&](int t, int buf) {
        const char* wbp = wl[buf];
        #pragma unroll
        for (int kk = 0; kk < 4; ++kk) {
            h16x8 a = load_a(aidx0 + t * 128 + kk * 32);
            h16x8 b0 = *(const h16x8*)(wbp + (      arow) * 256 + ((kk * 64 + g16 * 16) ^ xorv));
            h16x8 b1 = *(const h16x8*)(wbp + (16  + arow) * 256 + ((kk * 64 + g16 * 16) ^ xorv));
            h16x8 b2 = *(const h16x8*)(wbp + (32  + arow) * 256 + ((kk * 64 + g16 * 16) ^ xorv));
            acc0 = __builtin_amdgcn_mfma_f32_16x16x32_f16(a, b0, acc0, 0, 0, 0);
            acc1 = __builtin_amdgcn_mfma_f32_16x16x32_f16(a, b1, acc1, 0, 0, 0);
            acc2 = __builtin_amdgcn_mfma_f32_16x16x32_f16(a, b2, acc2, 0, 0, 0);
        }
    };

    // --- Prologue: tile0 staged; tiles 1,2 in flight (2-deep prefetch)
    int2 qA0 = wb0[0],   qA1 = wb1[0],   qA2 = wb2[0];
    __syncthreads();                    // scales visible
    cw(0, 0, qA0, qA1, qA2);
    qA0 = wb0[64];  qA1 = wb1[64];  qA2 = wb2[64];    // tile 1
    int2 qB0 = wb0[128], qB1 = wb1[128], qB2 = wb2[128]; // tile 2
    __syncthreads();                    // buf0 ready

    for (int t = 0; t < NT; t += 2) {
        // even: compute tile t from buf0, write tile t+1 -> buf1, issue tile t+3
        mfma_phase(t, 0);
        cw(1, t + 1, qA0, qA1, qA2);
        if (t + 3 < NT) {
            qA0 = wb0[(t + 3) * 64]; qA1 = wb1[(t + 3) * 64]; qA2 = wb2[(t + 3) * 64];
        }
        __syncthreads();
        // odd: compute tile t+1 from buf1, write tile t+2 -> buf0, issue tile t+4
        mfma_phase(t + 1, 1);
        if (t + 2 < NT) cw(0, t + 2, qB0, qB1, qB2);
        if (t + 4 < NT) {
            qB0 = wb0[(t + 4) * 64]; qB1 = wb1[(t + 4) * 64]; qB2 = wb2[(t + 4) * 64];
        }
        __syncthreads();
    }

    // --- Epilogue: D row = 4*(lane>>4)+r, col = lane&15 (m89-verified)
    float bv0 = bias[n0 +      arow];
    float bv1 = bias[n0 + 16 + arow];
    float bv2 = bias[n0 + 32 + arow];
    #pragma unroll
    for (int r = 0; r < 4; ++r) {
        int m = wave * 16 + g16 * 4 + r;
        float* op = out + (size_t)m * NDIM + n0 + arow;
        op[0]  = acc0[r] + bv0;
        op[16] = acc1[r] + bv1;
        op[32] = acc2[r] + bv2;
    }
}

extern "C" void kernel_launch(void* const* d_in, const int* in_sizes, int n_in,
                              void* d_out, int out_size, void* d_ws, size_t ws_size,
                              hipStream_t stream) {
    const float* x      = (const float*)d_in[0];
    const float* scales = (const float*)d_in[1];
    const float* bias   = (const float*)d_in[2];
    const int*   wq     = (const int*)d_in[3];
    float*       out    = (float*)d_out;

    const size_t xf_bytes = (size_t)MDIM * KDIM * sizeof(_Float16);  // 2 MB
    if (ws_size >= xf_bytes) {
        _Float16* xf = (_Float16*)d_ws;
        cvt_x_kernel<<<dim3(MDIM * KDIM / 1024), dim3(256), 0, stream>>>(x, xf);
        qlin_kernel<1><<<dim3(NDIM / N_TILE), dim3(1024), 0, stream>>>(x, xf, scales, bias, wq, out);
    } else {
        qlin_kernel<0><<<dim3(NDIM / N_TILE), dim3(1024), 0, stream>>>(x, nullptr, scales, bias, wq, out);
    }
}